// Round 1
// baseline (14397.833 us; speedup 1.0000x reference)
//
#include <hip/hip_runtime.h>
#include <math.h>

#define DEV __device__ __forceinline__

DEV float sigf(float x){ return 1.0f/(1.0f+__expf(-x)); }

// ---------------- embedding gather: x[b,s,:] = emb[tokens[b,s],:] ----------------
__global__ __launch_bounds__(256) void k_embed(const int* __restrict__ tok,
    const float* __restrict__ emb, float* __restrict__ x){
  int i = blockIdx.x*256 + threadIdx.x;      // 512*64*64 = 2097152 total
  int bs = i >> 6, d = i & 63;
  x[i] = emb[(size_t)tok[bs]*64 + d];
}

// ---------------- LSTM stage: z = [segA0|segA1|segA2] @ [W0;W1;W2] + bias, gates, h/c update ----
struct DirArgs {
  const float* A0; const float* A1; const float* A2;
  int sA0, sA1, sA2;             // row strides (floats)
  const float* W0; const float* W1; const float* W2;   // all [K,2048] row-major, ldw=2048
  int K0, K1, K2;
  const float* bias;             // [2048], gate order i,f,g,o in chunks of 512
  float* c;                      // [512,512] in-place
  float* h_out;                  // [512,512] ping-pong target
  float* out1;                   // layer1: f1/b1 + s*512 (row stride 32768), else nullptr
};

template<int NSEG>
__global__ __launch_bounds__(256) void k_lstm_stage(DirArgs fa, DirArgs ba){
  DirArgs A = blockIdx.z ? ba : fa;
  const float* Aseg[3] = {A.A0, A.A1, A.A2};
  int         sAseg[3] = {A.sA0, A.sA1, A.sA2};
  const float* Wseg[3] = {A.W0, A.W1, A.W2};
  int         Kseg[3] = {A.K0, A.K1, A.K2};

  __shared__ float As[16][68];     // [k][row], padded
  __shared__ float Ws[16][128];    // [k][gate*32 + cc]
  int tid = threadIdx.x;
  int m0 = blockIdx.y * 64;        // batch rows
  int j0 = blockIdx.x * 32;        // gate-col tile
  int ar = tid >> 2, akq = (tid & 3) * 4;   // A staging: row, k-quad
  int wk = tid >> 4, wi = (tid & 15) * 4;   // W staging: k-row, col-quad
  int ty = tid >> 4, tx = tid & 15;         // compute: 4 rows x (2 gate-cols x 4 gates)

  float acc[4][2][4];
  #pragma unroll
  for (int r=0;r<4;++r){
    #pragma unroll
    for (int j=0;j<2;++j){
      #pragma unroll
      for (int g=0;g<4;++g) acc[r][j][g]=0.f;
    }
  }

  #pragma unroll
  for (int seg = 0; seg < NSEG; ++seg){
    const float* Ap = Aseg[seg];
    const float* Wp = Wseg[seg];
    int sA = sAseg[seg];
    int K  = Kseg[seg];
    for (int k0 = 0; k0 < K; k0 += 16){
      float4 av = *(const float4*)(Ap + (size_t)(m0+ar)*sA + (k0+akq));
      int mc0 = wi, mc1 = wi + 64;
      const float* wrow = Wp + (size_t)(k0+wk)*2048 + j0;
      float4 w0 = *(const float4*)(wrow + (mc0>>5)*512 + (mc0&31));
      float4 w1 = *(const float4*)(wrow + (mc1>>5)*512 + (mc1&31));
      __syncthreads();
      As[akq+0][ar]=av.x; As[akq+1][ar]=av.y; As[akq+2][ar]=av.z; As[akq+3][ar]=av.w;
      *(float4*)&Ws[wk][mc0] = w0;
      *(float4*)&Ws[wk][mc1] = w1;
      __syncthreads();
      #pragma unroll
      for (int kk=0; kk<16; ++kk){
        float4 a4 = *(const float4*)&As[kk][ty*4];
        float a[4] = {a4.x, a4.y, a4.z, a4.w};
        #pragma unroll
        for (int g=0; g<4; ++g){
          float2 wg = *(const float2*)&Ws[kk][g*32 + tx*2];
          #pragma unroll
          for (int r=0;r<4;++r){
            acc[r][0][g] += a[r]*wg.x;
            acc[r][1][g] += a[r]*wg.y;
          }
        }
      }
    }
  }

  const float* bias = A.bias;
  #pragma unroll
  for (int r=0;r<4;++r){
    int row = m0 + ty*4 + r;
    #pragma unroll
    for (int jj=0;jj<2;++jj){
      int j = j0 + tx*2 + jj;
      float zi = acc[r][jj][0] + bias[j];
      float zf = acc[r][jj][1] + bias[512+j];
      float zg = acc[r][jj][2] + bias[1024+j];
      float zo = acc[r][jj][3] + bias[1536+j];
      size_t idx = (size_t)row*512 + j;
      float cn = sigf(zf)*A.c[idx] + sigf(zi)*tanhf(zg);
      float hn = sigf(zo)*tanhf(cn);
      A.c[idx] = cn;
      A.h_out[idx] = hn;
      if (A.out1) A.out1[(size_t)row*32768 + j] = hn;
    }
  }
}

// ---------------- generic fp32 GEMM: C = act(A[M,K]@W[K,N] + bias) ----------------
template<int ACT>   // 0 none, 1 relu
__global__ __launch_bounds__(256) void k_gemm(const float* __restrict__ A,
    const float* __restrict__ W, const float* __restrict__ bias,
    float* __restrict__ C, int K, int N){
  __shared__ float As[16][68];
  __shared__ float Ws[16][68];
  int tid=threadIdx.x;
  int m0=blockIdx.y*64, n0=blockIdx.x*64;
  int ar=tid>>2, akq=(tid&3)*4;
  int wk=tid>>4, wc=(tid&15)*4;
  int ty=tid>>4, tx=tid&15;
  float acc[4][4];
  #pragma unroll
  for(int r=0;r<4;++r){
    #pragma unroll
    for(int c=0;c<4;++c) acc[r][c]=0.f;
  }
  for(int k0=0;k0<K;k0+=16){
    float4 av=*(const float4*)(A+(size_t)(m0+ar)*K+(k0+akq));
    float4 wv=*(const float4*)(W+(size_t)(k0+wk)*N+(n0+wc));
    __syncthreads();
    As[akq+0][ar]=av.x; As[akq+1][ar]=av.y; As[akq+2][ar]=av.z; As[akq+3][ar]=av.w;
    *(float4*)&Ws[wk][wc]=wv;
    __syncthreads();
    #pragma unroll
    for(int kk=0;kk<16;++kk){
      float4 a4=*(const float4*)&As[kk][ty*4];
      float4 b4=*(const float4*)&Ws[kk][tx*4];
      float a[4]={a4.x,a4.y,a4.z,a4.w};
      float b[4]={b4.x,b4.y,b4.z,b4.w};
      #pragma unroll
      for(int r=0;r<4;++r){
        #pragma unroll
        for(int c=0;c<4;++c) acc[r][c]+=a[r]*b[c];
      }
    }
  }
  #pragma unroll
  for(int r=0;r<4;++r){
    int row=m0+ty*4+r;
    float o[4];
    #pragma unroll
    for(int c=0;c<4;++c){
      float v=acc[r][c]+bias[n0+tx*4+c];
      if(ACT==1) v=fmaxf(v,0.f);
      o[c]=v;
    }
    *(float4*)(C+(size_t)row*N+n0+tx*4) = make_float4(o[0],o[1],o[2],o[3]);
  }
}

// ---------------- concat final hidden states ----------------
__global__ __launch_bounds__(256) void k_concat(const float* __restrict__ hf,
    const float* __restrict__ hb, float* __restrict__ x2){
  int i = blockIdx.x*256+threadIdx.x;   // 512*1024
  int b = i>>10, j=i&1023;
  x2[i] = (j<512) ? hf[b*512+j] : hb[b*512 + (j-512)];
}

// ---------------- fused content-memory read (softmax(qK^T/8)V), per (b, mem) ----------------
__global__ __launch_bounds__(256) void k_memread(const float* __restrict__ query,
    const float* K0,const float* V0,const float* K1,const float* V1,
    const float* K2,const float* V2,const float* K3,const float* V3,
    const float* K4,const float* V4,const float* K5,const float* V5,
    float* __restrict__ reads){
  __shared__ float p[10016];
  __shared__ float qs[64];
  __shared__ float red[256];
  int b = blockIdx.x, mem = blockIdx.y, tid = threadIdx.x;
  const float* Kp; const float* Vp; int M;
  switch(mem){
    case 0: Kp=K0; Vp=V0; M=100;   break;
    case 1: Kp=K1; Vp=V1; M=1000;  break;
    case 2: Kp=K2; Vp=V2; M=500;   break;
    case 3: Kp=K3; Vp=V3; M=100;   break;
    case 4: Kp=K4; Vp=V4; M=10000; break;
    default:Kp=K5; Vp=V5; M=500;   break;
  }
  if (tid<64) qs[tid]=query[(size_t)b*64+tid];
  __syncthreads();
  float wt = 1.0f;
  if (mem==1){
    float t=0.f;
    #pragma unroll
    for(int i=0;i<6;++i) t+=qs[i];
    wt = sigf(t);
  }
  float lmax=-1e30f;
  for(int m=tid;m<M;m+=256){
    const float4* kr=(const float4*)(Kp+(size_t)m*64);
    float dot=0.f;
    #pragma unroll
    for(int i=0;i<16;++i){
      float4 kv=kr[i]; float4 qv=*(const float4*)&qs[i*4];
      dot += kv.x*qv.x+kv.y*qv.y+kv.z*qv.z+kv.w*qv.w;
    }
    dot *= 0.125f;
    p[m]=dot; lmax=fmaxf(lmax,dot);
  }
  red[tid]=lmax; __syncthreads();
  for (int s=128;s>0;s>>=1){ if (tid<s) red[tid]=fmaxf(red[tid],red[tid+s]); __syncthreads(); }
  float mx=red[0]; __syncthreads();
  float lsum=0.f;
  for(int m=tid;m<M;m+=256){ float e=__expf(p[m]-mx); p[m]=e; lsum+=e; }
  red[tid]=lsum; __syncthreads();
  for (int s=128;s>0;s>>=1){ if (tid<s) red[tid]+=red[tid+s]; __syncthreads(); }
  float sm=red[0]; __syncthreads();
  int d=tid&63, g=tid>>6;
  float av=0.f;
  for (int m=g;m<M;m+=4) av += p[m]*Vp[(size_t)m*64+d];
  red[tid]=av; __syncthreads();
  if (tid<64){
    float tot=red[tid]+red[tid+64]+red[tid+128]+red[tid+192];
    reads[((size_t)mem*512+b)*64+tid] = tot/sm*wt;
  }
}

__global__ __launch_bounds__(256) void k_meanreads(const float* __restrict__ reads,
    float* __restrict__ rmean){
  int i = blockIdx.x*256+threadIdx.x;   // 32768
  float s=0.f;
  #pragma unroll
  for(int mem=0;mem<6;++mem) s+=reads[(size_t)mem*32768 + i];
  rmean[i]=s*(1.0f/6.0f);
}

__global__ __launch_bounds__(256) void k_bn(const float* __restrict__ x,
    const float* __restrict__ g,const float* __restrict__ b,
    const float* __restrict__ m,const float* __restrict__ v,
    float* __restrict__ y){
  int i=blockIdx.x*256+threadIdx.x;   // 262144
  int j=i&511;
  y[i] = g[j]*(x[i]-m[j])*rsqrtf(v[j]+1e-3f)+b[j];
}

__global__ __launch_bounds__(256) void k_final(const float* __restrict__ x6,
    const float* __restrict__ foW, const float* __restrict__ fob,
    float* __restrict__ out){
  int b = blockIdx.x*256+threadIdx.x;  // 512
  float acc=fob[0];
  #pragma unroll 4
  for(int k=0;k<128;++k) acc += x6[(size_t)b*128+k]*foW[k];
  out[b] = 1.0f/(1.0f+__expf(-acc));
}

extern "C" void kernel_launch(void* const* d_in, const int* in_sizes, int n_in,
                              void* d_out, int out_size, void* d_ws, size_t ws_size,
                              hipStream_t stream){
  const int*   tokens = (const int*)  d_in[0];
  const float* emb    = (const float*)d_in[1];
  const float* l1f_Wi=(const float*)d_in[2], *l1f_Wh=(const float*)d_in[3], *l1f_b=(const float*)d_in[4];
  const float* l1b_Wi=(const float*)d_in[5], *l1b_Wh=(const float*)d_in[6], *l1b_b=(const float*)d_in[7];
  const float* l2f_Wi=(const float*)d_in[8], *l2f_Wh=(const float*)d_in[9], *l2f_b=(const float*)d_in[10];
  const float* l2b_Wi=(const float*)d_in[11],*l2b_Wh=(const float*)d_in[12],*l2b_b=(const float*)d_in[13];
  // d_in[14..17] = Wq,bq,Wk,bk: dead (softmax over a length-1 axis == 1, ctx == v)
  const float* Wv =(const float*)d_in[18], *bv =(const float*)d_in[19];
  const float* Wo =(const float*)d_in[20], *bo =(const float*)d_in[21];
  const float* mqW=(const float*)d_in[22], *mqb=(const float*)d_in[23];
  const float* extK =(const float*)d_in[24], *extV =(const float*)d_in[25];
  const float* formK=(const float*)d_in[26], *formV=(const float*)d_in[27];
  const float* concK=(const float*)d_in[28], *concV=(const float*)d_in[29];
  const float* stmK =(const float*)d_in[30], *stmV =(const float*)d_in[31];
  const float* ltmK =(const float*)d_in[32], *ltmV =(const float*)d_in[33];
  const float* infK =(const float*)d_in[34], *infV =(const float*)d_in[35];
  const float* rsW=(const float*)d_in[36], *rsb=(const float*)d_in[37];
  const float* bng=(const float*)d_in[38], *bnb=(const float*)d_in[39];
  const float* bnm=(const float*)d_in[40], *bnv=(const float*)d_in[41];
  const float* stW=(const float*)d_in[42], *stb=(const float*)d_in[43];
  const float* foW=(const float*)d_in[44], *fob=(const float*)d_in[45];
  float* out = (float*)d_out;

  float* ws = (float*)d_ws;
  const size_t S = 262144;                // 512*512
  float* hf[2]  = {ws+0*S, ws+1*S};
  float* hb[2]  = {ws+2*S, ws+3*S};
  float* cf = ws+4*S;  float* cb = ws+5*S;
  float* h2f[2] = {ws+6*S, ws+7*S};
  float* h2b[2] = {ws+8*S, ws+9*S};
  float* c2f = ws+10*S; float* c2b = ws+11*S;
  float* x     = ws+12*S;                 // [512,64,64]   8S
  float* f1    = ws+20*S;                 // [512,64,512]  64S
  float* b1    = ws+84*S;                 // [512,64,512]  64S
  float* x2    = ws+148*S;                // [512,1024]    2S
  float* vb    = ws+150*S;                // [512,512]     1S
  float* x3    = ws+151*S;                // [512,1024]    2S
  float* query = ws+153*S;                // [512,64]
  float* reads = query+32768;             // [6,512,64]
  float* rmean = reads+196608;            // [512,64]
  float* x4    = rmean+32768;             // [512,512]
  float* x5    = x4+S;                    // [512,512]
  float* x6    = x5+S;                    // [512,128]

  // zero LSTM states (h ping-pong + c), laid out contiguously at ws start
  hipMemsetAsync(ws, 0, 12*S*sizeof(float), stream);

  k_embed<<<2097152/256, 256, 0, stream>>>(tokens, emb, x);

  // ---- layer 1 (f + b concurrently), store all h into f1/b1 ----
  for (int t=0; t<64; ++t){
    int s = 63-t;
    DirArgs fa{}, ba{};
    fa.A0 = x + (size_t)t*64;  fa.sA0 = 4096; fa.W0 = l1f_Wi; fa.K0 = 64;
    fa.A1 = hf[t&1];           fa.sA1 = 512;  fa.W1 = l1f_Wh; fa.K1 = 512;
    fa.A2 = nullptr; fa.sA2 = 0; fa.W2 = nullptr; fa.K2 = 0;
    fa.bias = l1f_b; fa.c = cf; fa.h_out = hf[(t+1)&1]; fa.out1 = f1 + (size_t)t*512;
    ba.A0 = x + (size_t)s*64;  ba.sA0 = 4096; ba.W0 = l1b_Wi; ba.K0 = 64;
    ba.A1 = hb[t&1];           ba.sA1 = 512;  ba.W1 = l1b_Wh; ba.K1 = 512;
    ba.A2 = nullptr; ba.sA2 = 0; ba.W2 = nullptr; ba.K2 = 0;
    ba.bias = l1b_b; ba.c = cb; ba.h_out = hb[(t+1)&1]; ba.out1 = b1 + (size_t)s*512;
    k_lstm_stage<2><<<dim3(16,8,2), 256, 0, stream>>>(fa, ba);
  }
  // ---- layer 2 (f + b concurrently), only final h needed ----
  for (int t=0; t<64; ++t){
    int s = 63-t;
    DirArgs fa{}, ba{};
    fa.A0 = f1 + (size_t)t*512; fa.sA0 = 32768; fa.W0 = l2f_Wi;            fa.K0 = 512;
    fa.A1 = b1 + (size_t)t*512; fa.sA1 = 32768; fa.W1 = l2f_Wi + 512*2048; fa.K1 = 512;
    fa.A2 = h2f[t&1];           fa.sA2 = 512;   fa.W2 = l2f_Wh;            fa.K2 = 512;
    fa.bias = l2f_b; fa.c = c2f; fa.h_out = h2f[(t+1)&1]; fa.out1 = nullptr;
    ba.A0 = f1 + (size_t)s*512; ba.sA0 = 32768; ba.W0 = l2b_Wi;            ba.K0 = 512;
    ba.A1 = b1 + (size_t)s*512; ba.sA1 = 32768; ba.W1 = l2b_Wi + 512*2048; ba.K1 = 512;
    ba.A2 = h2b[t&1];           ba.sA2 = 512;   ba.W2 = l2b_Wh;            ba.K2 = 512;
    ba.bias = l2b_b; ba.c = c2b; ba.h_out = h2b[(t+1)&1]; ba.out1 = nullptr;
    k_lstm_stage<3><<<dim3(16,8,2), 256, 0, stream>>>(fa, ba);
  }

  // ---- head ----
  k_concat<<<524288/256, 256, 0, stream>>>(h2f[0], h2b[0], x2);
  k_gemm<0><<<dim3(8,8),  256, 0, stream>>>(x2,    Wv,  bv,  vb,    1024, 512);   // v = x2@Wv+bv (attn ctx == v)
  k_gemm<0><<<dim3(16,8), 256, 0, stream>>>(vb,    Wo,  bo,  x3,    512,  1024);  // x3 = v@Wo+bo
  k_gemm<0><<<dim3(1,8),  256, 0, stream>>>(x3,    mqW, mqb, query, 1024, 64);    // query
  k_memread<<<dim3(512,6), 256, 0, stream>>>(query, extK,extV, formK,formV, concK,concV,
                                             stmK,stmV, ltmK,ltmV, infK,infV, reads);
  k_meanreads<<<32768/256, 256, 0, stream>>>(reads, rmean);
  k_gemm<1><<<dim3(8,8),  256, 0, stream>>>(rmean, rsW, rsb, x4,    64,   512);   // relu(rmean@rs_W+rs_b)
  k_bn<<<262144/256, 256, 0, stream>>>(x4, bng, bnb, bnm, bnv, x5);
  k_gemm<0><<<dim3(2,8),  256, 0, stream>>>(x5,    stW, stb, x6,    512,  128);   // st
  k_final<<<2, 256, 0, stream>>>(x6, foW, fob, out);
}

// Round 3
// 6540.672 us; speedup vs baseline: 2.2013x; 2.2013x over previous
//
#include <hip/hip_runtime.h>
#include <math.h>

#define DEV __device__ __forceinline__

typedef __attribute__((ext_vector_type(8))) short short8v;   // 8 bf16 = 4 VGPRs
typedef __attribute__((ext_vector_type(4))) float f32x4;

DEV float sigf(float x){ return 1.0f/(1.0f+__expf(-x)); }

DEV void split_bf16(float v, short& hi, short& lo){
  union { float f; unsigned u; } a; a.f = v;
  unsigned rh = (a.u + 0x7FFFu + ((a.u >> 16) & 1u)) >> 16;   // rne to bf16
  hi = (short)rh;
  union { unsigned u; float f; } b; b.u = rh << 16;
  a.f = v - b.f;
  unsigned rl = (a.u + 0x7FFFu + ((a.u >> 16) & 1u)) >> 16;
  lo = (short)rl;
}

// ---------------- embedding gather ----------------
__global__ __launch_bounds__(256) void k_embed(const int* __restrict__ tok,
    const float* __restrict__ emb, float* __restrict__ x){
  int i = blockIdx.x*256 + threadIdx.x;      // 512*64*64
  int bs = i >> 6, d = i & 63;
  x[i] = emb[(size_t)tok[bs]*64 + d];
}

// ---------------- weight transpose + bf16 hi/lo split: W[K][2048] -> WT[2048][Ktot] ----
__global__ __launch_bounds__(256) void k_tsplit(const float* __restrict__ W,
    short* __restrict__ wth, short* __restrict__ wtl, int Ktot, int kbase){
  __shared__ float tile[32][33];
  int k0 = blockIdx.x*32, n0 = blockIdx.y*32;
  int tx = threadIdx.x & 31, ty = threadIdx.x >> 5;
  for (int r = ty; r < 32; r += 8)
    tile[r][tx] = W[(size_t)(k0+r)*2048 + n0 + tx];
  __syncthreads();
  for (int r = ty; r < 32; r += 8){
    int n = n0 + r;
    short hi, lo; split_bf16(tile[tx][r], hi, lo);
    size_t idx = (size_t)n*Ktot + kbase + k0 + tx;
    wth[idx] = hi; wtl[idx] = lo;
  }
}

// ---------------- MFMA LSTM stage (bf16x3 split) ----------------
struct StageArgs {
  const float *A0, *A1, *A2;     // activation segments (fp32)
  int s0, s1, s2;                // row strides (floats)
  int k1, k2;                    // global-k start of seg1/seg2
  const short *wth, *wtl;        // WT [2048][Ktot] bf16 hi/lo, k-contiguous
  int Ktot;
  const float* bias;             // [2048] gate order i,f,g,o
  float* c; float* hout; float* out1;
};

struct SMemStage {
  union {
    struct {
      short Ah[64][40];          // [row][k], +8 pad (2-way banks = free)
      short Al[64][40];
      short Bh[128][40];         // [interleaved col][k]; col c = jj*4+gate
      short Bl[128][40];
    } st;
    float z[64][128];            // epilogue gate exchange
  };
};

template<int NSEG>
DEV const float* a_ptr(const StageArgs& A, int k, int rowoff){
  if (NSEG == 2){
    if (k < A.k1) return A.A0 + (size_t)rowoff*A.s0 + k;
    return A.A1 + (size_t)rowoff*A.s1 + (k - A.k1);
  } else {
    if (k < A.k1) return A.A0 + (size_t)rowoff*A.s0 + k;
    if (k < A.k2) return A.A1 + (size_t)rowoff*A.s1 + (k - A.k1);
    return A.A2 + (size_t)rowoff*A.s2 + (k - A.k2);
  }
}

template<int NSEG>
__global__ __launch_bounds__(256) void k_lstm_mfma(StageArgs fa, StageArgs ba){
  StageArgs A = blockIdx.z ? ba : fa;
  __shared__ SMemStage s;
  const int tid = threadIdx.x;
  const int lane = tid & 63, w = tid >> 6;
  const int wr = w >> 1, wc = w & 1;                    // 2x2 waves, wave tile 32x64
  const int m0 = blockIdx.y * 64, j0 = blockIdx.x * 32;
  // A staging: 64 rows x 32 k fp32 -> split
  const int sArow = tid >> 2, sAoff = (tid & 3) * 8;
  // B staging: 128 interleaved cols x 32 k, thread covers one (row, hi|lo)
  const int sBrow = tid >> 1, sBpart = tid & 1;
  const int nB = (sBrow & 3) * 512 + j0 + (sBrow >> 2); // gate*512 + j0 + jj
  const short* wtB = (sBpart ? A.wtl : A.wth) + (size_t)nB * A.Ktot;
  // fragment addresses
  const int fAr = wr*32 + (lane & 15), fk = (lane >> 4) * 8;
  const int fBc = wc*64 + (lane & 15);

  f32x4 acc[2][4];
  #pragma unroll
  for (int i=0;i<2;++i)
    #pragma unroll
    for (int j=0;j<4;++j) acc[i][j] = 0.f;

  // prefetch k0 = 0
  float4 av0, av1; short8v bv[4];
  {
    const float* ap = a_ptr<NSEG>(A, 0, m0 + sArow) + sAoff;
    av0 = *(const float4*)ap; av1 = *(const float4*)(ap+4);
    #pragma unroll
    for (int i=0;i<4;++i) bv[i] = *(const short8v*)(wtB + i*8);
  }

  for (int k0 = 0; k0 < A.Ktot; k0 += 32){
    __syncthreads();
    // write staged regs to LDS
    {
      float a8[8] = {av0.x,av0.y,av0.z,av0.w,av1.x,av1.y,av1.z,av1.w};
      short8v h8, l8;
      #pragma unroll
      for (int i=0;i<8;++i){ short hh, ll; split_bf16(a8[i], hh, ll); h8[i]=hh; l8[i]=ll; }
      *(short8v*)&s.st.Ah[sArow][sAoff] = h8;
      *(short8v*)&s.st.Al[sArow][sAoff] = l8;
      short (*Bp)[40] = sBpart ? s.st.Bl : s.st.Bh;
      #pragma unroll
      for (int i=0;i<4;++i) *(short8v*)&Bp[sBrow][i*8] = bv[i];
    }
    __syncthreads();
    // prefetch next k-step (hidden under MFMAs)
    int kn = k0 + 32;
    if (kn < A.Ktot){
      const float* ap = a_ptr<NSEG>(A, kn, m0 + sArow) + sAoff;
      av0 = *(const float4*)ap; av1 = *(const float4*)(ap+4);
      #pragma unroll
      for (int i=0;i<4;++i) bv[i] = *(const short8v*)(wtB + kn + i*8);
    }
    // fragments + MFMA (3-term split: ah*bh + ah*bl + al*bh)
    short8v ah[2], al[2], bh[4], bl[4];
    #pragma unroll
    for (int mf=0;mf<2;++mf){
      ah[mf] = *(const short8v*)&s.st.Ah[fAr + mf*16][fk];
      al[mf] = *(const short8v*)&s.st.Al[fAr + mf*16][fk];
    }
    #pragma unroll
    for (int nf=0;nf<4;++nf){
      bh[nf] = *(const short8v*)&s.st.Bh[fBc + nf*16][fk];
      bl[nf] = *(const short8v*)&s.st.Bl[fBc + nf*16][fk];
    }
    #pragma unroll
    for (int mf=0;mf<2;++mf)
      #pragma unroll
      for (int nf=0;nf<4;++nf){
        acc[mf][nf] = __builtin_amdgcn_mfma_f32_16x16x32_bf16(ah[mf], bh[nf], acc[mf][nf], 0,0,0);
        acc[mf][nf] = __builtin_amdgcn_mfma_f32_16x16x32_bf16(ah[mf], bl[nf], acc[mf][nf], 0,0,0);
        acc[mf][nf] = __builtin_amdgcn_mfma_f32_16x16x32_bf16(al[mf], bh[nf], acc[mf][nf], 0,0,0);
      }
  }

  __syncthreads();
  // z exchange: D row = (lane>>4)*4 + r, col = lane&15 within 16x16 frag
  #pragma unroll
  for (int mf=0;mf<2;++mf)
    #pragma unroll
    for (int nf=0;nf<4;++nf)
      #pragma unroll
      for (int r=0;r<4;++r)
        s.z[wr*32 + mf*16 + (lane>>4)*4 + r][wc*64 + nf*16 + (lane&15)] = acc[mf][nf][r];
  __syncthreads();

  // gate pass: thread -> (row, 8 jj's)
  {
    int row = tid >> 2, jjq = (tid & 3) * 8;
    size_t rbase = (size_t)(m0+row)*512 + j0;
    #pragma unroll
    for (int q=0;q<2;++q){
      int jj4 = jjq + q*4;
      float4 cold = *(const float4*)(A.c + rbase + jj4);
      float co[4] = {cold.x, cold.y, cold.z, cold.w};
      float hn[4], cn[4];
      #pragma unroll
      for (int e=0;e<4;++e){
        int jj = jj4 + e, n = j0 + jj;
        float4 zv = *(const float4*)&s.z[row][jj*4];
        float zi = zv.x + A.bias[n];
        float zf = zv.y + A.bias[512+n];
        float zg = zv.z + A.bias[1024+n];
        float zo = zv.w + A.bias[1536+n];
        float cc = sigf(zf)*co[e] + sigf(zi)*tanhf(zg);
        cn[e] = cc; hn[e] = sigf(zo)*tanhf(cc);
      }
      *(float4*)(A.c    + rbase + jj4) = make_float4(cn[0],cn[1],cn[2],cn[3]);
      *(float4*)(A.hout + rbase + jj4) = make_float4(hn[0],hn[1],hn[2],hn[3]);
      if (A.out1)
        *(float4*)(A.out1 + (size_t)(m0+row)*32768 + j0 + jj4) = make_float4(hn[0],hn[1],hn[2],hn[3]);
    }
  }
}

// ---------------- generic fp32 GEMM (head, small) ----------------
template<int ACT>
__global__ __launch_bounds__(256) void k_gemm(const float* __restrict__ A,
    const float* __restrict__ W, const float* __restrict__ bias,
    float* __restrict__ C, int K, int N){
  __shared__ float As[16][68];
  __shared__ float Ws[16][68];
  int tid=threadIdx.x;
  int m0=blockIdx.y*64, n0=blockIdx.x*64;
  int ar=tid>>2, akq=(tid&3)*4;
  int wk=tid>>4, wcq=(tid&15)*4;
  int ty=tid>>4, tx=tid&15;
  float acc[4][4];
  #pragma unroll
  for(int r=0;r<4;++r){ 
    #pragma unroll
    for(int c=0;c<4;++c) acc[r][c]=0.f; }
  for(int k0=0;k0<K;k0+=16){
    float4 av=*(const float4*)(A+(size_t)(m0+ar)*K+(k0+akq));
    float4 wv=*(const float4*)(W+(size_t)(k0+wk)*N+(n0+wcq));
    __syncthreads();
    As[akq+0][ar]=av.x; As[akq+1][ar]=av.y; As[akq+2][ar]=av.z; As[akq+3][ar]=av.w;
    *(float4*)&Ws[wk][wcq]=wv;
    __syncthreads();
    #pragma unroll
    for(int kk=0;kk<16;++kk){
      float4 a4=*(const float4*)&As[kk][ty*4];
      float4 b4=*(const float4*)&Ws[kk][tx*4];
      float a[4]={a4.x,a4.y,a4.z,a4.w};
      float b[4]={b4.x,b4.y,b4.z,b4.w};
      #pragma unroll
      for(int r=0;r<4;++r){
        #pragma unroll
        for(int c=0;c<4;++c) acc[r][c]+=a[r]*b[c]; }
    }
  }
  #pragma unroll
  for(int r=0;r<4;++r){
    int row=m0+ty*4+r;
    float o[4];
    #pragma unroll
    for(int c=0;c<4;++c){
      float v=acc[r][c]+bias[n0+tx*4+c];
      if(ACT==1) v=fmaxf(v,0.f);
      o[c]=v;
    }
    *(float4*)(C+(size_t)row*N+n0+tx*4) = make_float4(o[0],o[1],o[2],o[3]);
  }
}

__global__ __launch_bounds__(256) void k_concat(const float* __restrict__ hf,
    const float* __restrict__ hb, float* __restrict__ x2){
  int i = blockIdx.x*256+threadIdx.x;   // 512*1024
  int b = i>>10, j=i&1023;
  x2[i] = (j<512) ? hf[b*512+j] : hb[b*512 + (j-512)];
}

// ---------------- chunked memory read, phase 1: per-(chunk, 8 batch) partials ----
__global__ __launch_bounds__(256) void k_mem_part(const float* __restrict__ query,
    const float* K0,const float* V0,const float* K1,const float* V1,
    const float* K2,const float* V2,const float* K3,const float* V3,
    const float* K4,const float* V4,const float* K5,const float* V5,
    float* __restrict__ parts){
  int chunk = blockIdx.x, b0 = blockIdx.y*8, tid = threadIdx.x;
  const float *Kp, *Vp; int mstart, mcnt;
  if      (chunk==0){ Kp=K0; Vp=V0; mstart=0;              mcnt=100; }
  else if (chunk<5) { Kp=K1; Vp=V1; mstart=(chunk-1)*250;  mcnt=250; }
  else if (chunk<7) { Kp=K2; Vp=V2; mstart=(chunk-5)*250;  mcnt=250; }
  else if (chunk==7){ Kp=K3; Vp=V3; mstart=0;              mcnt=100; }
  else if (chunk<48){ Kp=K4; Vp=V4; mstart=(chunk-8)*250;  mcnt=250; }
  else              { Kp=K5; Vp=V5; mstart=(chunk-48)*250; mcnt=250; }
  __shared__ float qs[8][64];
  __shared__ float p[8][256];
  __shared__ float red[4][8][64];
  __shared__ float mv[8], sv[8];
  ((float*)qs)[tid]     = query[(size_t)b0*64 + tid];
  ((float*)qs)[tid+256] = query[(size_t)b0*64 + 256 + tid];
  __syncthreads();
  float dot[8] = {0,0,0,0,0,0,0,0};
  if (tid < mcnt){
    const float4* kr = (const float4*)(Kp + (size_t)(mstart+tid)*64);
    #pragma unroll 4
    for (int i=0;i<16;++i){
      float4 kv = kr[i];
      #pragma unroll
      for (int mb=0;mb<8;++mb){
        float4 qv = *(const float4*)&qs[mb][i*4];
        dot[mb] += kv.x*qv.x + kv.y*qv.y + kv.z*qv.z + kv.w*qv.w;
      }
    }
  }
  #pragma unroll
  for (int mb=0;mb<8;++mb) p[mb][tid] = dot[mb]*0.125f;
  __syncthreads();
  { // per-mb softmax stats via 32-lane groups
    int mb = tid >> 5, l32 = tid & 31;
    float mx = -1e30f;
    #pragma unroll
    for (int j=0;j<8;++j){ int m = l32 + j*32; if (m < mcnt) mx = fmaxf(mx, p[mb][m]); }
    for (int d=16; d; d>>=1) mx = fmaxf(mx, __shfl_xor(mx, d, 32));
    float sum = 0.f;
    #pragma unroll
    for (int j=0;j<8;++j){ int m = l32 + j*32;
      if (m < mcnt){ float e = __expf(p[mb][m]-mx); p[mb][m]=e; sum+=e; } }
    for (int d=16; d; d>>=1) sum += __shfl_xor(sum, d, 32);
    if (l32==0){ mv[mb]=mx; sv[mb]=sum; }
  }
  __syncthreads();
  int d = tid & 63, g = tid >> 6;
  float pv[8] = {0,0,0,0,0,0,0,0};
  for (int m=g; m<mcnt; m+=4){
    float vv = Vp[(size_t)(mstart+m)*64 + d];
    #pragma unroll
    for (int mb=0;mb<8;++mb) pv[mb] += p[mb][m]*vv;
  }
  #pragma unroll
  for (int mb=0;mb<8;++mb) red[g][mb][d] = pv[mb];
  __syncthreads();
  for (int i=tid; i<512; i+=256){
    int mb = i >> 6, dd = i & 63;
    float tot = red[0][mb][dd]+red[1][mb][dd]+red[2][mb][dd]+red[3][mb][dd];
    parts[((size_t)(b0+mb)*50 + chunk)*68 + dd] = tot;
  }
  if (tid < 8){
    parts[((size_t)(b0+tid)*50 + chunk)*68 + 64] = mv[tid];
    parts[((size_t)(b0+tid)*50 + chunk)*68 + 65] = sv[tid];
  }
}

// ---------------- memory read, phase 2: combine chunks ----------------
__global__ __launch_bounds__(64) void k_mem_comb(const float* __restrict__ query,
    const float* __restrict__ parts, float* __restrict__ reads){
  int b = blockIdx.x, d = threadIdx.x;
  const int c0s[6] = {0,1,5,7,8,48};
  const int c1s[6] = {1,5,7,8,48,50};
  float t = 0.f;
  #pragma unroll
  for (int i=0;i<6;++i) t += query[(size_t)b*64+i];
  float wt1 = sigf(t);
  for (int mem=0; mem<6; ++mem){
    float gmax = -1e30f;
    for (int c=c0s[mem]; c<c1s[mem]; ++c)
      gmax = fmaxf(gmax, parts[((size_t)b*50+c)*68 + 64]);
    float pv=0.f, tot=0.f;
    for (int c=c0s[mem]; c<c1s[mem]; ++c){
      const float* pc = parts + ((size_t)b*50+c)*68;
      float sc = __expf(pc[64]-gmax);
      pv  += sc*pc[d];
      tot += sc*pc[65];
    }
    float r = pv/tot * (mem==1 ? wt1 : 1.0f);
    reads[((size_t)mem*512+b)*64 + d] = r;
  }
}

__global__ __launch_bounds__(256) void k_meanreads(const float* __restrict__ reads,
    float* __restrict__ rmean){
  int i = blockIdx.x*256+threadIdx.x;   // 32768
  float sm=0.f;
  #pragma unroll
  for(int mem=0;mem<6;++mem) sm+=reads[(size_t)mem*32768 + i];
  rmean[i]=sm*(1.0f/6.0f);
}

__global__ __launch_bounds__(256) void k_bn(const float* __restrict__ x,
    const float* __restrict__ g,const float* __restrict__ b,
    const float* __restrict__ m,const float* __restrict__ v,
    float* __restrict__ y){
  int i=blockIdx.x*256+threadIdx.x;   // 262144
  int j=i&511;
  y[i] = g[j]*(x[i]-m[j])*rsqrtf(v[j]+1e-3f)+b[j];
}

__global__ __launch_bounds__(256) void k_final(const float* __restrict__ x6,
    const float* __restrict__ foW, const float* __restrict__ fob,
    float* __restrict__ out){
  int b = blockIdx.x*256+threadIdx.x;  // 512
  float acc=fob[0];
  #pragma unroll 4
  for(int k=0;k<128;++k) acc += x6[(size_t)b*128+k]*foW[k];
  out[b] = 1.0f/(1.0f+__expf(-acc));
}

extern "C" void kernel_launch(void* const* d_in, const int* in_sizes, int n_in,
                              void* d_out, int out_size, void* d_ws, size_t ws_size,
                              hipStream_t stream){
  const int*   tokens = (const int*)  d_in[0];
  const float* emb    = (const float*)d_in[1];
  const float* l1f_Wi=(const float*)d_in[2], *l1f_Wh=(const float*)d_in[3], *l1f_b=(const float*)d_in[4];
  const float* l1b_Wi=(const float*)d_in[5], *l1b_Wh=(const float*)d_in[6], *l1b_b=(const float*)d_in[7];
  const float* l2f_Wi=(const float*)d_in[8], *l2f_Wh=(const float*)d_in[9], *l2f_b=(const float*)d_in[10];
  const float* l2b_Wi=(const float*)d_in[11],*l2b_Wh=(const float*)d_in[12],*l2b_b=(const float*)d_in[13];
  // d_in[14..17] = Wq,bq,Wk,bk: dead (softmax over length-1 axis == 1, ctx == v)
  const float* Wv =(const float*)d_in[18], *bv =(const float*)d_in[19];
  const float* Wo =(const float*)d_in[20], *bo =(const float*)d_in[21];
  const float* mqW=(const float*)d_in[22], *mqb=(const float*)d_in[23];
  const float* extK =(const float*)d_in[24], *extV =(const float*)d_in[25];
  const float* formK=(const float*)d_in[26], *formV=(const float*)d_in[27];
  const float* concK=(const float*)d_in[28], *concV=(const float*)d_in[29];
  const float* stmK =(const float*)d_in[30], *stmV =(const float*)d_in[31];
  const float* ltmK =(const float*)d_in[32], *ltmV =(const float*)d_in[33];
  const float* infK =(const float*)d_in[34], *infV =(const float*)d_in[35];
  const float* rsW=(const float*)d_in[36], *rsb=(const float*)d_in[37];
  const float* bng=(const float*)d_in[38], *bnb=(const float*)d_in[39];
  const float* bnm=(const float*)d_in[40], *bnv=(const float*)d_in[41];
  const float* stW=(const float*)d_in[42], *stb=(const float*)d_in[43];
  const float* foW=(const float*)d_in[44], *fob=(const float*)d_in[45];
  float* out = (float*)d_out;

  float* ws = (float*)d_ws;
  const size_t S = 262144;               // 512*512 floats
  float* hf[2]  = {ws+0*S, ws+1*S};
  float* hb[2]  = {ws+2*S, ws+3*S};
  float* cf = ws+4*S;  float* cb = ws+5*S;
  float* h2f[2] = {ws+6*S, ws+7*S};
  float* h2b[2] = {ws+8*S, ws+9*S};
  float* c2f = ws+10*S; float* c2b = ws+11*S;
  float* x     = ws+12*S;                // [512,64,64]
  float* f1    = ws+20*S;                // [512,64,512] fp32
  float* b1    = ws+84*S;                // [512,64,512]
  float* x2    = ws+148*S;               // [512,1024]
  float* vbuf  = ws+150*S;               // [512,512]
  float* x3    = ws+151*S;               // [512,1024]
  float* query = ws+153*S;               // [512,64]
  float* reads = query+32768;            // [6,512,64]
  float* rmean = reads+196608;           // [512,64]
  float* x4    = rmean+32768;            // [512,512]
  float* x5    = x4+S;                   // [512,512]
  float* x6    = x5+S;                   // [512,128]
  float* parts = x6+65536;               // [512,50,68]
  short* wt    = (short*)(parts + (size_t)512*50*68);
  short* l1fH = wt;                 short* l1fL = l1fH + (size_t)2048*576;
  short* l1bH = l1fL + (size_t)2048*576;  short* l1bL = l1bH + (size_t)2048*576;
  short* l2fH = l1bL + (size_t)2048*576;  short* l2fL = l2fH + (size_t)2048*1536;
  short* l2bH = l2fL + (size_t)2048*1536; short* l2bL = l2bH + (size_t)2048*1536;

  hipMemsetAsync(ws, 0, 12*S*sizeof(float), stream);     // h/c states

  // weight transpose + split (once per launch)
  k_tsplit<<<dim3(2,64),  256, 0, stream>>>(l1f_Wi, l1fH, l1fL, 576, 0);
  k_tsplit<<<dim3(16,64), 256, 0, stream>>>(l1f_Wh, l1fH, l1fL, 576, 64);
  k_tsplit<<<dim3(2,64),  256, 0, stream>>>(l1b_Wi, l1bH, l1bL, 576, 0);
  k_tsplit<<<dim3(16,64), 256, 0, stream>>>(l1b_Wh, l1bH, l1bL, 576, 64);
  k_tsplit<<<dim3(32,64), 256, 0, stream>>>(l2f_Wi, l2fH, l2fL, 1536, 0);
  k_tsplit<<<dim3(16,64), 256, 0, stream>>>(l2f_Wh, l2fH, l2fL, 1536, 1024);
  k_tsplit<<<dim3(32,64), 256, 0, stream>>>(l2b_Wi, l2bH, l2bL, 1536, 0);
  k_tsplit<<<dim3(16,64), 256, 0, stream>>>(l2b_Wh, l2bH, l2bL, 1536, 1024);

  k_embed<<<2097152/256, 256, 0, stream>>>(tokens, emb, x);

  // ---- layer 1 ----
  for (int t=0; t<64; ++t){
    int sr = 63-t;
    StageArgs fa{}, ba{};
    fa.A0 = x + (size_t)t*64;  fa.s0 = 4096;
    fa.A1 = hf[t&1];           fa.s1 = 512;
    fa.k1 = 64; fa.k2 = 0;
    fa.wth = l1fH; fa.wtl = l1fL; fa.Ktot = 576; fa.bias = l1f_b;
    fa.c = cf; fa.hout = hf[(t+1)&1]; fa.out1 = f1 + (size_t)t*512;
    ba.A0 = x + (size_t)sr*64; ba.s0 = 4096;
    ba.A1 = hb[t&1];           ba.s1 = 512;
    ba.k1 = 64; ba.k2 = 0;
    ba.wth = l1bH; ba.wtl = l1bL; ba.Ktot = 576; ba.bias = l1b_b;
    ba.c = cb; ba.hout = hb[(t+1)&1]; ba.out1 = b1 + (size_t)sr*512;
    k_lstm_mfma<2><<<dim3(16,8,2), 256, 0, stream>>>(fa, ba);
  }
  // ---- layer 2 ----
  for (int t=0; t<64; ++t){
    int sr = 63-t;
    StageArgs fa{}, ba{};
    fa.A0 = f1 + (size_t)t*512; fa.s0 = 32768;
    fa.A1 = b1 + (size_t)t*512; fa.s1 = 32768;
    fa.A2 = h2f[t&1];           fa.s2 = 512;
    fa.k1 = 512; fa.k2 = 1024;
    fa.wth = l2fH; fa.wtl = l2fL; fa.Ktot = 1536; fa.bias = l2f_b;
    fa.c = c2f; fa.hout = h2f[(t+1)&1]; fa.out1 = nullptr;
    ba.A0 = f1 + (size_t)sr*512; ba.s0 = 32768;
    ba.A1 = b1 + (size_t)sr*512; ba.s1 = 32768;
    ba.A2 = h2b[t&1];            ba.s2 = 512;
    ba.k1 = 512; ba.k2 = 1024;
    ba.wth = l2bH; ba.wtl = l2bL; ba.Ktot = 1536; ba.bias = l2b_b;
    ba.c = c2b; ba.hout = h2b[(t+1)&1]; ba.out1 = nullptr;
    k_lstm_mfma<3><<<dim3(16,8,2), 256, 0, stream>>>(fa, ba);
  }

  // ---- head ----
  k_concat<<<524288/256, 256, 0, stream>>>(h2f[0], h2b[0], x2);
  k_gemm<0><<<dim3(8,8),  256, 0, stream>>>(x2,    Wv,  bv,  vbuf,  1024, 512);
  k_gemm<0><<<dim3(16,8), 256, 0, stream>>>(vbuf,  Wo,  bo,  x3,    512,  1024);
  k_gemm<0><<<dim3(1,8),  256, 0, stream>>>(x3,    mqW, mqb, query, 1024, 64);
  k_mem_part<<<dim3(50,64), 256, 0, stream>>>(query, extK,extV, formK,formV, concK,concV,
                                              stmK,stmV, ltmK,ltmV, infK,infV, parts);
  k_mem_comb<<<512, 64, 0, stream>>>(query, parts, reads);
  k_meanreads<<<32768/256, 256, 0, stream>>>(reads, rmean);
  k_gemm<1><<<dim3(8,8),  256, 0, stream>>>(rmean, rsW, rsb, x4,    64,   512);
  k_bn<<<262144/256, 256, 0, stream>>>(x4, bng, bnb, bnm, bnv, x5);
  k_gemm<0><<<dim3(2,8),  256, 0, stream>>>(x5,    stW, stb, x6,    512,  128);
  k_final<<<2, 256, 0, stream>>>(x6, foW, fob, out);
}